// Round 11
// baseline (124.426 us; speedup 1.0000x reference)
//
#include <hip/hip_runtime.h>
#include <hip/hip_bf16.h>

// LinearGaussianSystem via Woodbury:
//   M  = R + H Pinv H^T                  (16x16, per batch)
//   sweep(M) -> -M^-1 = -Q  (in-place sweep operator, 16 steps, no RHS)
//   T' = (-Q)(0.5G)kdup = -T             (stage-1 MFMA)
//   Sigma = Pinv + (0.5Gt)kdup*T' = Pinv - Gt*T    (stage-2 MFMA, A sign = +)
//   mu = mu0 + T'^T (c - y) = mu0 + T^T (y - c)
// 8 lanes/batch in the solve (lane owns M cols g, g+8): the 16 ds_swizzle
// broadcasts per sweep step serve 8 batches/wave.
// Round-11 changes vs round 10:
//  - Sigma stored TRANSPOSED via symmetry: each f32x4 MFMA result is a
//    contiguous row chunk -> 4 float4 stores/lane/batch instead of 16 scalar.
//  - T' double-buffered in a separate per-wave LDS area (both tiles written,
//    ONE fence, both read, 4 stage-2 MFMAs clustered). 40 KB LDS total.
//  - Mean stored by lanes l<32 as one contiguous 128B store.
//
// ws layout (floats / u32):
//   0    : Acm[16][16]   A=(H Pinv)H^T column-major
//   768  : af[2][64][4]  stage-2 A-frags (+0.5*Gt, k-dup), packed bf16 pairs
//   1280 : pf[4][64][4]  Pinv C/D-layout frags, tile t=(r*2+c)
//   2304 : bgf[2][64][4] stage-1 B-frags (0.5*G, k-dup), packed bf16 pairs
//   2816 : cvec[16]      bias + H mu0
//   2832 : m0v[32]       mu0

typedef __attribute__((ext_vector_type(8))) short bf16x8;
typedef __attribute__((ext_vector_type(4))) float f32x4;

__device__ __forceinline__ unsigned bf16rne(float f) {
    unsigned x = __float_as_uint(f);
    return (x + 0x7FFFu + ((x >> 16) & 1u)) >> 16;
}
__device__ __forceinline__ unsigned pack2(float a, float b) {
    return bf16rne(a) | (bf16rne(b) << 16);
}

__global__ void lgs_setup(const float* __restrict__ H, const float* __restrict__ bias,
                          const float* __restrict__ mu0, const float* __restrict__ P,
                          float* __restrict__ ws)
{
    __shared__ float aug[32][65];   // [P | I] augmented, padded stride 65
    __shared__ float colk[32];
    __shared__ float Gs[16][32];    // G  = H Pinv
    __shared__ float Gts[32][16];   // Gt = Pinv H^T
    const int tid = threadIdx.x;    // 256 threads

    for (int idx = tid; idx < 2048; idx += 256) {
        int r = idx >> 6, c = idx & 63;
        aug[r][c] = (c < 32) ? P[r * 32 + c] : (((c - 32) == r) ? 1.0f : 0.0f);
    }
    __syncthreads();

    // Gauss-Jordan inversion of P (SPD -> no pivoting). Thread tid<64 owns column tid.
    for (int k = 0; k < 32; ++k) {
        if (tid < 32) colk[tid] = aug[tid][k];
        __syncthreads();
        if (tid < 64) {
            float rk = aug[k][tid] * (1.0f / colk[k]);
            aug[k][tid] = rk;
            for (int r = 0; r < 32; ++r)
                if (r != k) aug[r][tid] -= colk[r] * rk;
        }
        __syncthreads();
    }
    // Pinv[r][c] = aug[r][32+c]

    for (int idx = tid; idx < 512; idx += 256) {
        int o = idx >> 5, s = idx & 31;
        float acc = 0.f;
        for (int v = 0; v < 32; ++v) acc += H[o * 32 + v] * aug[v][32 + s];
        Gs[o][s] = acc;
    }
    for (int idx = tid; idx < 512; idx += 256) {
        int s = idx >> 4, o = idx & 15;
        float acc = 0.f;
        for (int v = 0; v < 32; ++v) acc += aug[s][32 + v] * H[o * 32 + v];
        Gts[s][o] = acc;
    }
    __syncthreads();

    for (int idx = tid; idx < 256; idx += 256) {      // Acm[j][i] = A[i][j]
        int j = idx >> 4, i = idx & 15;
        float acc = 0.f;
        for (int s = 0; s < 32; ++s) acc += Gs[i][s] * H[j * 32 + s];
        ws[idx] = acc;
    }
    unsigned* wsu = (unsigned*)ws;
    // stage-2 A-frags: af[r][l][j] = pack(+0.5*Gt[16r+(l&15)][kb], ..[kb+1]),
    // kb = ((l>>4)*8 + 2j) & 15  (k duplicated across halves). Sign + because
    // the B operand will be T' = -T.
    for (int idx = tid; idx < 512; idx += 256) {
        int r = idx >> 8, rem = idx & 255;
        int l = rem >> 2, j = rem & 3;
        int mm = 16 * r + (l & 15);
        int kb = (((l >> 4) * 8) + 2 * j) & 15;
        wsu[768 + idx] = pack2(0.5f * Gts[mm][kb], 0.5f * Gts[mm][kb + 1]);
    }
    // Pinv frags in MFMA C/D layout: pf[t][l][j] = Pinv[16*(t>>1)+((l>>4)*4)+j][16*(t&1)+(l&15)]
    for (int idx = tid; idx < 1024; idx += 256) {
        int tt = idx >> 8, rem = idx & 255;
        int l = rem >> 2, j = rem & 3;
        int row = 16 * (tt >> 1) + ((l >> 4) << 2) + j;
        int col = 16 * (tt & 1) + (l & 15);
        ws[1280 + idx] = aug[row][32 + col];
    }
    // stage-1 B-frags: bgf[c][l][j2] = pack(0.5*G[k][16c+(l&15)], 0.5*G[k+1][..]),
    // k = ((l>>4)*8 + 2*j2) & 15
    for (int idx = tid; idx < 512; idx += 256) {
        int c = idx >> 8, rem = idx & 255;
        int l = rem >> 2, j2 = rem & 3;
        int col = 16 * c + (l & 15);
        int k = (((l >> 4) * 8) + 2 * j2) & 15;
        wsu[2304 + idx] = pack2(0.5f * Gs[k][col], 0.5f * Gs[k + 1][col]);
    }
    if (tid < 16) {
        float acc = bias[tid];
        for (int s = 0; s < 32; ++s) acc += H[tid * 32 + s] * mu0[s];
        ws[2816 + tid] = acc;
    }
    if (tid < 32) ws[2832 + tid] = mu0[tid];
}

// Broadcast x from lane K of each 8-lane group (BitMode: and=0x18 keeps the
// two group bits within each 32-half, or=K).
#define BCAST8(x, K) __int_as_float(__builtin_amdgcn_ds_swizzle(__float_as_int(x), (((K) << 5) | 0x18)))

// Sweep operator step on M (in place). Lane (l&7) owns columns (l&7) and
// (l&7)+8 in m0/m1. After steps 0..15, {m0,m1} hold -M^-1 columns.
template <int K>
__device__ __forceinline__ void sweep_step(int l, float (&m0)[16], float (&m1)[16])
{
    const bool own = (l & 7) == (K & 7);
    float (&mp)[16] = (K >> 3) ? m1 : m0;   // array holding the pivot column
    float (&mo)[16] = (K >> 3) ? m0 : m1;   // the other owned column
    if (own) mp[K] = 1.0f / mp[K];          // owner publishes invd in slot K
    float bc[16];
#pragma unroll
    for (int i = 0; i < 16; ++i) bc[i] = BCAST8(mp[i], K & 7);
    // bc[K] = invd; bc[i!=K] = old pivot-column entries m[i][K]
    float fp = own ? 0.0f : mp[K] * bc[K];  // pivot-array factor (0 on owner)
    float fo = mo[K] * bc[K];
#pragma unroll
    for (int i = 0; i < 16; ++i) {
        if (i != K) { mp[i] -= bc[i] * fp; mo[i] -= bc[i] * fo; }
    }
    mp[K] = fp;
    mo[K] = fo;
    if (own) {                              // pivot column: m[i][K] -> m[i][K]/d
        float invd = bc[K];
#pragma unroll
        for (int i = 0; i < 16; ++i) mp[i] = bc[i] * invd;
        mp[K] = -invd;
    }
}

__global__ __launch_bounds__(512, 2) void lgs_main(
    const float* __restrict__ obs, const float* __restrict__ noise,
    const float* __restrict__ ws,
    float* __restrict__ out_mean, float* __restrict__ out_cov, int B)
{
    // [0..8191]      : 64 slots x 128 u32 (512B) bf16 Q staging
    // [8192..10239]  : 8 waves x 256 u32 (1KB) T' double-buffer (tile0|tile1)
    __shared__ unsigned ldu[10240];

    const int tid  = threadIdx.x;
    const int l    = tid & 63;                       // lane
    const int wv   = tid >> 6;                       // wave (0..7)
    const int g    = l & 7;                          // owned column pair {g, g+8}
    const int slot = wv * 8 + (l >> 3);              // batch slot (0..63)
    const int b    = blockIdx.x * 64 + slot;
    const int bb   = (b < B) ? b : (B - 1);

    const float* __restrict__ Acm  = ws;
    const float* __restrict__ cvec = ws + 2816;
    const float* __restrict__ m0v  = ws + 2832;

    float m0[16], m1[16];

    // M columns g, g+8 (R symmetric -> rows g, g+8 contiguous).
    const float4* Rr0 = (const float4*)(noise + (size_t)bb * 256 + g * 16);
    const float4* Ar0 = (const float4*)(Acm + g * 16);
    const float4* Rr1 = (const float4*)(noise + (size_t)bb * 256 + (g + 8) * 16);
    const float4* Ar1 = (const float4*)(Acm + (g + 8) * 16);
#pragma unroll
    for (int i = 0; i < 4; ++i) {
        float4 r = Rr0[i], a = Ar0[i];
        m0[4*i+0] = r.x + a.x; m0[4*i+1] = r.y + a.y;
        m0[4*i+2] = r.z + a.z; m0[4*i+3] = r.w + a.w;
        float4 r1 = Rr1[i], a1 = Ar1[i];
        m1[4*i+0] = r1.x + a1.x; m1[4*i+1] = r1.y + a1.y;
        m1[4*i+2] = r1.z + a1.z; m1[4*i+3] = r1.w + a1.w;
    }

    sweep_step<0>(l, m0, m1);   sweep_step<1>(l, m0, m1);
    sweep_step<2>(l, m0, m1);   sweep_step<3>(l, m0, m1);
    sweep_step<4>(l, m0, m1);   sweep_step<5>(l, m0, m1);
    sweep_step<6>(l, m0, m1);   sweep_step<7>(l, m0, m1);
    sweep_step<8>(l, m0, m1);   sweep_step<9>(l, m0, m1);
    sweep_step<10>(l, m0, m1);  sweep_step<11>(l, m0, m1);
    sweep_step<12>(l, m0, m1);  sweep_step<13>(l, m0, m1);
    sweep_step<14>(l, m0, m1);  sweep_step<15>(l, m0, m1);

    // Stage Q' = -Q columns g, g+8 as bf16 k-pairs. Position p^(c&4) holds
    // pair p (uint4-aligned XOR). (g+8)&4 == g&4, so one x0 serves both.
    {
        unsigned* qb = &ldu[slot * 128 + g * 8];
        const int x0 = g & 4;
        *(uint4*)&qb[x0]      = make_uint4(pack2(m0[0],m0[1]),  pack2(m0[2],m0[3]),
                                           pack2(m0[4],m0[5]),  pack2(m0[6],m0[7]));
        *(uint4*)&qb[x0 ^ 4]  = make_uint4(pack2(m0[8],m0[9]),  pack2(m0[10],m0[11]),
                                           pack2(m0[12],m0[13]), pack2(m0[14],m0[15]));
        *(uint4*)&qb[64 + x0] = make_uint4(pack2(m1[0],m1[1]),  pack2(m1[2],m1[3]),
                                           pack2(m1[4],m1[5]),  pack2(m1[6],m1[7]));
        *(uint4*)&qb[64 + (x0 ^ 4)] = make_uint4(pack2(m1[8],m1[9]),  pack2(m1[10],m1[11]),
                                                 pack2(m1[12],m1[13]), pack2(m1[14],m1[15]));
    }
    asm volatile("" ::: "memory");   // pin Q write -> read program order

    // Constant frags (L1-hot). pfr tiles intentionally NOT hoisted.
    const uint4*  AF4 = (const uint4*)(ws + 768);
    const uint4*  BG4 = (const uint4*)(ws + 2304);
    const float4* PF4 = (const float4*)(ws + 1280);
    uint4 a0u = AF4[l], a1u = AF4[64 + l];
    uint4 g0u = BG4[l], g1u = BG4[64 + l];
    bf16x8 A0, A1, Bg0, Bg1;
    __builtin_memcpy(&A0,  &a0u, 16);
    __builtin_memcpy(&A1,  &a1u, 16);
    __builtin_memcpy(&Bg0, &g0u, 16);
    __builtin_memcpy(&Bg1, &g1u, 16);

    const int ch   = l & 15;                 // output column within tile
    const int gp   = l >> 4;                 // k-group 0..3
    const int qoff = ch * 8 + (((gp & 1) * 4) ^ (ch & 4));   // Q uint4 pos
    const int xt   = (ch & 1) << 2;
    const int g2   = gp * 2;
    const int kp   = (gp & 1) * 4;
    const float4 cv = ((const float4*)cvec)[gp];
    const float mu0a = m0v[ch], mu0b = m0v[16 + ch];
    const f32x4 zero = {0.f, 0.f, 0.f, 0.f};
    unsigned* tw = &ldu[8192 + wv * 256];    // per-wave T' area: tile0 | tile1

#pragma unroll
    for (int h = 0; h < 8; ++h) {
        const int sh  = wv * 8 + h;
        const int bh  = blockIdx.x * 64 + sh;
        const int bhc = (bh < B) ? bh : (B - 1);
        unsigned* tb = &ldu[sh * 128];

        // Stage-1 A-frag: Q' col ch (= row ch by symmetry), k-quarter
        uint4 qu = *(const uint4*)&tb[qoff];
        bf16x8 Qa; __builtin_memcpy(&Qa, &qu, 16);
        f32x4 d0 = __builtin_amdgcn_mfma_f32_16x16x32_bf16(Qa, Bg0, zero, 0, 0, 0);
        f32x4 d1 = __builtin_amdgcn_mfma_f32_16x16x32_bf16(Qa, Bg1, zero, 0, 0, 0);
        // d_c[j] = T'_c[row = gp*4+j][col = ch],  T' = -Q*G

        // posterior mean: mu = mu0 + T'^T (c - y)
        float4 yv = *(const float4*)(obs + (size_t)bhc * 16 + gp * 4);
        float z0 = cv.x - yv.x, z1 = cv.y - yv.y, z2 = cv.z - yv.z, z3 = cv.w - yv.w;
        float p0 = d0[0]*z0 + d0[1]*z1 + d0[2]*z2 + d0[3]*z3;
        float p1 = d1[0]*z0 + d1[1]*z1 + d1[2]*z2 + d1[3]*z3;
        p0 += __int_as_float(__builtin_amdgcn_ds_swizzle(__float_as_int(p0), 0x401F));
        p1 += __int_as_float(__builtin_amdgcn_ds_swizzle(__float_as_int(p1), 0x401F));
        p0 += __shfl_xor(p0, 32, 64);
        p1 += __shfl_xor(p1, 32, 64);
        if (bh < B && l < 32) {
            // lanes 0..15: cols 0..15 (=ch); lanes 16..31: cols 16..31
            float muv = (l < 16) ? (mu0a + p0) : (mu0b + p1);
            out_mean[(size_t)bh * 32 + l] = muv;   // one contiguous 128B store
        }

        // Both T' tiles -> per-wave double-buffer area, ONE fence, read both.
        *(uint2*)&tw[ch * 8 + (g2 ^ xt)] =
            make_uint2(pack2(d0[0], d0[1]), pack2(d0[2], d0[3]));
        *(uint2*)&tw[128 + ch * 8 + (g2 ^ xt)] =
            make_uint2(pack2(d1[0], d1[1]), pack2(d1[2], d1[3]));
        asm volatile("" ::: "memory");
        uint4 bu0 = *(const uint4*)&tw[ch * 8 + (kp ^ xt)];
        uint4 bu1 = *(const uint4*)&tw[128 + ch * 8 + (kp ^ xt)];
        bf16x8 Bf0, Bf1;
        __builtin_memcpy(&Bf0, &bu0, 16);
        __builtin_memcpy(&Bf1, &bu1, 16);

        float4 pq0 = PF4[l];
        float4 pq1 = PF4[64 + l];
        float4 pq2 = PF4[128 + l];
        float4 pq3 = PF4[192 + l];
        f32x4 pfr0; pfr0[0]=pq0.x; pfr0[1]=pq0.y; pfr0[2]=pq0.z; pfr0[3]=pq0.w;
        f32x4 pfr1; pfr1[0]=pq1.x; pfr1[1]=pq1.y; pfr1[2]=pq1.z; pfr1[3]=pq1.w;
        f32x4 pfr2; pfr2[0]=pq2.x; pfr2[1]=pq2.y; pfr2[2]=pq2.z; pfr2[3]=pq2.w;
        f32x4 pfr3; pfr3[0]=pq3.x; pfr3[1]=pq3.y; pfr3[2]=pq3.z; pfr3[3]=pq3.w;
        f32x4 s00 = __builtin_amdgcn_mfma_f32_16x16x32_bf16(A0, Bf0, pfr0, 0, 0, 0);
        f32x4 s01 = __builtin_amdgcn_mfma_f32_16x16x32_bf16(A0, Bf1, pfr1, 0, 0, 0);
        f32x4 s10 = __builtin_amdgcn_mfma_f32_16x16x32_bf16(A1, Bf0, pfr2, 0, 0, 0);
        f32x4 s11 = __builtin_amdgcn_mfma_f32_16x16x32_bf16(A1, Bf1, pfr3, 0, 0, 0);

        // Sigma symmetric: s00[j] = Sigma[gp*4+j][ch] = Sigma[ch][gp*4+j] ->
        // each f32x4 is a contiguous row chunk. 4 float4 stores per lane.
        if (bh < B) {
            float* Sb = out_cov + (size_t)bh * 1024;
            const int cb = gp * 4;
            *(float4*)&Sb[ch * 32 + cb] =
                make_float4(s00[0], s00[1], s00[2], s00[3]);
            *(float4*)&Sb[ch * 32 + 16 + cb] =
                make_float4(s10[0], s10[1], s10[2], s10[3]);
            *(float4*)&Sb[(16 + ch) * 32 + cb] =
                make_float4(s01[0], s01[1], s01[2], s01[3]);
            *(float4*)&Sb[(16 + ch) * 32 + 16 + cb] =
                make_float4(s11[0], s11[1], s11[2], s11[3]);
        }
    }
}

extern "C" void kernel_launch(void* const* d_in, const int* in_sizes, int n_in,
                              void* d_out, int out_size, void* d_ws, size_t ws_size,
                              hipStream_t stream)
{
    const float* obs   = (const float*)d_in[0];   // [B,16]
    const float* noise = (const float*)d_in[1];   // [B,16,16]
    const float* H     = (const float*)d_in[2];   // [16,32]
    const float* bias  = (const float*)d_in[3];   // [16]
    const float* mu0   = (const float*)d_in[4];   // [32]
    const float* P     = (const float*)d_in[5];   // [32,32]
    float* ws = (float*)d_ws;

    const int B = in_sizes[0] / 16;
    float* out_mean = (float*)d_out;
    float* out_cov  = out_mean + (size_t)B * 32;

    lgs_setup<<<1, 256, 0, stream>>>(H, bias, mu0, P, ws);
    lgs_main<<<(B + 63) / 64, 512, 0, stream>>>(obs, noise, ws, out_mean, out_cov, B);
}

// Round 12
// 109.384 us; speedup vs baseline: 1.1375x; 1.1375x over previous
//
#include <hip/hip_runtime.h>
#include <hip/hip_bf16.h>

// LinearGaussianSystem via Woodbury:
//   M  = R + H Pinv H^T                  (16x16, per batch)
//   Q  = M^-1  (per batch, column-GJ on [M | I], 16 lanes/batch)
//   T  = Q G               (stage-1 MFMA: A = Q bf16, B = 0.5*G const, k-dup)
//   Sigma = Pinv - G^T T   (stage-2 MFMA: A = -0.5*Gt const, B = T bf16, C = Pinv)
//   mu = mu0 + T^T z, z = y - c  (stage-1 fp32 D + xor16/xor32 reduce)
// Main kernel = round-8 structure verbatim (best measured: 115.4 us).
// Round-12 change: lgs_setup rebuilt as ONE 64-lane wave, ZERO barriers:
//  - [P|I] has exactly 64 columns -> lane c owns column c in 32 registers;
//    column-GJ with __shfl pivot-column broadcasts, fully unrolled.
//  - Pinv symmetric => Gt = G^T: G computed once (old setup did both).
//  - frag packing off LDS with compiler fences only (same-wave DS in-order).
//
// ws layout (floats / u32):
//   0    : Acm[16][16]   A=(H Pinv)H^T column-major
//   768  : af[2][64][4]  stage-2 A-frags (-0.5*Gt, k-dup), packed bf16 pairs
//   1280 : pf[4][64][4]  Pinv C/D-layout frags, tile t=(r*2+c)
//   2304 : bgf[2][64][4] stage-1 B-frags (0.5*G, k-dup), packed bf16 pairs
//   2816 : cvec[16]      bias + H mu0
//   2832 : m0v[32]       mu0

typedef __attribute__((ext_vector_type(8))) short bf16x8;
typedef __attribute__((ext_vector_type(4))) float f32x4;

__device__ __forceinline__ unsigned bf16rne(float f) {
    unsigned x = __float_as_uint(f);
    return (x + 0x7FFFu + ((x >> 16) & 1u)) >> 16;
}
__device__ __forceinline__ unsigned pack2(float a, float b) {
    return bf16rne(a) | (bf16rne(b) << 16);
}

__global__ void lgs_setup(const float* __restrict__ H, const float* __restrict__ bias,
                          const float* __restrict__ mu0, const float* __restrict__ P,
                          float* __restrict__ ws)
{
    // One wave (64 threads). No __syncthreads anywhere.
    __shared__ float pinv[32][33];   // pinv[c][i] = Pinv[i][c] (padded)
    __shared__ float Gsh[16][33];    // G[o][s] = (H Pinv)[o][s] (padded)
    const int l = threadIdx.x;       // 0..63

    // Lane l owns column l of aug = [P | I] (64 columns total).
    float m[32];
#pragma unroll
    for (int i = 0; i < 32; ++i)
        m[i] = (l < 32) ? P[i * 32 + l] : ((i == (l - 32)) ? 1.0f : 0.0f);

    // Column-GJ, fully unrolled (static register indexing). Pivot column k
    // lives in lane k; broadcast its 32 entries via shfl. SPD -> no pivoting.
#pragma unroll
    for (int k = 0; k < 32; ++k) {
        float bc[32];
#pragma unroll
        for (int i = 0; i < 32; ++i) bc[i] = __shfl(m[i], k, 64);
        float a = m[k] * (1.0f / bc[k]);
#pragma unroll
        for (int i = 0; i < 32; ++i)
            if (i != k) m[i] -= bc[i] * a;
        m[k] = a;
    }
    // Lanes 32..63 now hold Pinv columns: lane 32+c has Pinv[:,c].
    if (l >= 32) {
        const int c = l - 32;
#pragma unroll
        for (int i = 0; i < 32; ++i) pinv[c][i] = m[i];
    }
    asm volatile("" ::: "memory");   // same-wave DS is in-order

    // G[o][s] = sum_u H[o][u] Pinv[u][s]   (Gt = G^T by Pinv symmetry)
    for (int idx = l; idx < 512; idx += 64) {
        int o = idx >> 5, s = idx & 31;
        float acc = 0.f;
        for (int u = 0; u < 32; ++u) acc += H[o * 32 + u] * pinv[s][u];
        Gsh[o][s] = acc;
    }
    asm volatile("" ::: "memory");

    // Acm[j][i] = A[i][j] = sum_s G[i][s] H[j][s]
    for (int idx = l; idx < 256; idx += 64) {
        int j = idx >> 4, i = idx & 15;
        float acc = 0.f;
        for (int s = 0; s < 32; ++s) acc += Gsh[i][s] * H[j * 32 + s];
        ws[idx] = acc;
    }
    unsigned* wsu = (unsigned*)ws;
    // stage-2 A-frags: af[r][ll][j] = pack(-0.5*Gt[16r+(ll&15)][kb], ..[kb+1]),
    // kb = ((ll>>4)*8 + 2j) & 15; Gt[s][o] = G[o][s]
    for (int idx = l; idx < 512; idx += 64) {
        int r = idx >> 8, rem = idx & 255;
        int ll = rem >> 2, j = rem & 3;
        int mm = 16 * r + (ll & 15);
        int kb = (((ll >> 4) * 8) + 2 * j) & 15;
        wsu[768 + idx] = pack2(-0.5f * Gsh[kb][mm], -0.5f * Gsh[kb + 1][mm]);
    }
    // Pinv frags in MFMA C/D layout:
    // pf[t][ll][j] = Pinv[16*(t>>1)+((ll>>4)*4)+j][16*(t&1)+(ll&15)]
    for (int idx = l; idx < 1024; idx += 64) {
        int tt = idx >> 8, rem = idx & 255;
        int ll = rem >> 2, j = rem & 3;
        int row = 16 * (tt >> 1) + ((ll >> 4) << 2) + j;
        int col = 16 * (tt & 1) + (ll & 15);
        ws[1280 + idx] = pinv[col][row];
    }
    // stage-1 B-frags: bgf[c][ll][j2] = pack(0.5*G[k][16c+(ll&15)], 0.5*G[k+1][..]),
    // k = ((ll>>4)*8 + 2*j2) & 15
    for (int idx = l; idx < 512; idx += 64) {
        int c = idx >> 8, rem = idx & 255;
        int ll = rem >> 2, j2 = rem & 3;
        int col = 16 * c + (ll & 15);
        int k = (((ll >> 4) * 8) + 2 * j2) & 15;
        wsu[2304 + idx] = pack2(0.5f * Gsh[k][col], 0.5f * Gsh[k + 1][col]);
    }
    if (l < 16) {
        float acc = bias[l];
        for (int s = 0; s < 32; ++s) acc += H[l * 32 + s] * mu0[s];
        ws[2816 + l] = acc;
    }
    if (l < 32) ws[2832 + l] = mu0[l];
}

// Broadcast x from lane K of each 16-lane group (BitMode: and=0x10 keeps the
// group bit within each 32-half, or=K).
#define BCAST16(x, K) __int_as_float(__builtin_amdgcn_ds_swizzle(__float_as_int(x), (((K) << 5) | 0x10)))

// Column-GJ on [M | I]. Lane t owns M column t and Q column t (starts e_t).
template <int K>
__device__ __forceinline__ void gj16(int t, float (&m)[16], float (&v)[16])
{
    if (t == K) m[K] = 1.0f / m[K];   // owner publishes inv-pivot in slot K
    float bc[16];
#pragma unroll
    for (int i = 0; i < 16; ++i) bc[i] = BCAST16(m[i], K);
    float pk = m[K] * bc[K];          // meaningful for cols t>K; dead elsewhere
#pragma unroll
    for (int i = 0; i < 16; ++i)
        if (i != K) m[i] -= bc[i] * pk;
    m[K] = pk;
    float a = v[K] * bc[K];
#pragma unroll
    for (int i = 0; i < 16; ++i)
        if (i != K) v[i] -= bc[i] * a;
    v[K] = a;
}

__global__ __launch_bounds__(512, 4) void lgs_main(
    const float* __restrict__ obs, const float* __restrict__ noise,
    const float* __restrict__ ws,
    float* __restrict__ out_mean, float* __restrict__ out_cov, int B)
{
    // 32 slots x 256 floats (1 KB): Q staging, then reused for bf16 T. 32 KB.
    __shared__ float ld[8192];

    const int tid  = threadIdx.x;
    const int l    = tid & 63;                       // lane
    const int t    = tid & 15;                       // column owner
    const int slot = tid >> 4;                       // batch slot (0..31)
    const int wv   = tid >> 6;                       // wave (0..7)
    const int b    = blockIdx.x * 32 + slot;
    const int bb   = (b < B) ? b : (B - 1);

    const float* __restrict__ Acm  = ws;
    const float* __restrict__ cvec = ws + 2816;
    const float* __restrict__ m0v  = ws + 2832;

    float m[16], v[16];

    // M column t = R column t + A column t (R symmetric -> read row t, contiguous).
    const float4* Rr = (const float4*)(noise + (size_t)bb * 256 + t * 16);
    const float4* Ar = (const float4*)(Acm + t * 16);
#pragma unroll
    for (int i = 0; i < 4; ++i) {
        float4 r = Rr[i], a = Ar[i];
        m[4*i+0] = r.x + a.x; m[4*i+1] = r.y + a.y;
        m[4*i+2] = r.z + a.z; m[4*i+3] = r.w + a.w;
    }
#pragma unroll
    for (int i = 0; i < 16; ++i) v[i] = (i == t) ? 1.0f : 0.0f;

    gj16<0>(t, m, v);   gj16<1>(t, m, v);   gj16<2>(t, m, v);   gj16<3>(t, m, v);
    gj16<4>(t, m, v);   gj16<5>(t, m, v);   gj16<6>(t, m, v);   gj16<7>(t, m, v);
    gj16<8>(t, m, v);   gj16<9>(t, m, v);   gj16<10>(t, m, v);  gj16<11>(t, m, v);
    gj16<12>(t, m, v);  gj16<13>(t, m, v);  gj16<14>(t, m, v);  gj16<15>(t, m, v);

    // Stage Q col t (quarter-XOR swizzled; wave-private slot, no barrier needed).
    {
        const int xw = t & 3;
        float* wb = &ld[slot * 256 + t * 16];
        *(float4*)&wb[(0 ^ xw) << 2] = make_float4(v[0],  v[1],  v[2],  v[3]);
        *(float4*)&wb[(1 ^ xw) << 2] = make_float4(v[4],  v[5],  v[6],  v[7]);
        *(float4*)&wb[(2 ^ xw) << 2] = make_float4(v[8],  v[9],  v[10], v[11]);
        *(float4*)&wb[(3 ^ xw) << 2] = make_float4(v[12], v[13], v[14], v[15]);
    }

    // Constant frags (L1-hot)
    const uint4*  AF4 = (const uint4*)(ws + 768);
    const uint4*  BG4 = (const uint4*)(ws + 2304);
    const float4* PF4 = (const float4*)(ws + 1280);
    uint4 a0u = AF4[l], a1u = AF4[64 + l];
    uint4 g0u = BG4[l], g1u = BG4[64 + l];
    bf16x8 A0, A1, Bg0, Bg1;
    __builtin_memcpy(&A0,  &a0u, 16);
    __builtin_memcpy(&A1,  &a1u, 16);
    __builtin_memcpy(&Bg0, &g0u, 16);
    __builtin_memcpy(&Bg1, &g1u, 16);
    float4 pq;
    f32x4 pfr0, pfr1, pfr2, pfr3;
    pq = PF4[l];        pfr0[0]=pq.x; pfr0[1]=pq.y; pfr0[2]=pq.z; pfr0[3]=pq.w;
    pq = PF4[64 + l];   pfr1[0]=pq.x; pfr1[1]=pq.y; pfr1[2]=pq.z; pfr1[3]=pq.w;
    pq = PF4[128 + l];  pfr2[0]=pq.x; pfr2[1]=pq.y; pfr2[2]=pq.z; pfr2[3]=pq.w;
    pq = PF4[192 + l];  pfr3[0]=pq.x; pfr3[1]=pq.y; pfr3[2]=pq.z; pfr3[3]=pq.w;

    const int ch = l & 15;           // output column within tile
    const int gp = l >> 4;           // k-group 0..3
    const int gq = (gp & 1) * 2;     // Q quarter base (k duplicated)
    const int xq = ch & 3;           // Q read XOR
    const int xt = (ch & 1) << 2;    // T pair XOR
    const float4 cv = ((const float4*)cvec)[gp];
    const float mu0a = m0v[ch], mu0b = m0v[16 + ch];
    const f32x4 zero = {0.f, 0.f, 0.f, 0.f};

#pragma unroll
    for (int h = 0; h < 4; ++h) {
        const int sh  = wv * 4 + h;                  // this wave's slot
        const int bh  = blockIdx.x * 32 + sh;
        const int bhc = (bh < B) ? bh : (B - 1);

        // Stage-1 A-frag: A[row=ch][k] = Q[ch][k&15] = staged col ch (symmetry)
        const float* qb = &ld[sh * 256 + ch * 16];
        float4 qa = *(const float4*)&qb[((gq    ) ^ xq) << 2];
        float4 qc = *(const float4*)&qb[((gq + 1) ^ xq) << 2];
        unsigned qarr[4] = { pack2(qa.x, qa.y), pack2(qa.z, qa.w),
                             pack2(qc.x, qc.y), pack2(qc.z, qc.w) };
        bf16x8 Qa; __builtin_memcpy(&Qa, qarr, 16);
        f32x4 d0 = __builtin_amdgcn_mfma_f32_16x16x32_bf16(Qa, Bg0, zero, 0, 0, 0);
        f32x4 d1 = __builtin_amdgcn_mfma_f32_16x16x32_bf16(Qa, Bg1, zero, 0, 0, 0);
        // d_c[j] = T_c[row = gp*4+j][col = ch],  T = Q*G

        // posterior mean: mu[16c+ch] = mu0 + sum_i T_c[i][ch] * z[i]
        float4 yv = *(const float4*)(obs + (size_t)bhc * 16 + gp * 4);
        float z0 = yv.x - cv.x, z1 = yv.y - cv.y, z2 = yv.z - cv.z, z3 = yv.w - cv.w;
        float p0 = d0[0]*z0 + d0[1]*z1 + d0[2]*z2 + d0[3]*z3;
        float p1 = d1[0]*z0 + d1[1]*z1 + d1[2]*z2 + d1[3]*z3;
        p0 += __int_as_float(__builtin_amdgcn_ds_swizzle(__float_as_int(p0), 0x401F));
        p1 += __int_as_float(__builtin_amdgcn_ds_swizzle(__float_as_int(p1), 0x401F));
        p0 += __shfl_xor(p0, 32, 64);
        p1 += __shfl_xor(p1, 32, 64);
        if (bh < B) {
            if (gp == 0) out_mean[(size_t)bh * 32 + ch]      = mu0a + p0;
            if (gp == 1) out_mean[(size_t)bh * 32 + 16 + ch] = mu0b + p1;
        }

        // T -> LDS as bf16 pairs (overwrites this slot's Q; same-wave order).
        unsigned* tb = (unsigned*)&ld[sh * 256];
        const int g2 = gp * 2;
        *(uint2*)&tb[      ch * 8 + (g2 ^ xt)] =
            make_uint2(pack2(d0[0], d0[1]), pack2(d0[2], d0[3]));
        *(uint2*)&tb[128 + ch * 8 + (g2 ^ xt)] =
            make_uint2(pack2(d1[0], d1[1]), pack2(d1[2], d1[3]));

        // Stage-2 B-frag: B[k][col=ch] = T_c[k&15][ch]
        const int kp = (gp & 1) * 4;
        uint4 bu0 = *(const uint4*)&tb[      ch * 8 + (kp ^ xt)];
        uint4 bu1 = *(const uint4*)&tb[128 + ch * 8 + (kp ^ xt)];
        bf16x8 Bf0, Bf1;
        __builtin_memcpy(&Bf0, &bu0, 16);
        __builtin_memcpy(&Bf1, &bu1, 16);
        f32x4 s00 = __builtin_amdgcn_mfma_f32_16x16x32_bf16(A0, Bf0, pfr0, 0, 0, 0);
        f32x4 s01 = __builtin_amdgcn_mfma_f32_16x16x32_bf16(A0, Bf1, pfr1, 0, 0, 0);
        f32x4 s10 = __builtin_amdgcn_mfma_f32_16x16x32_bf16(A1, Bf0, pfr2, 0, 0, 0);
        f32x4 s11 = __builtin_amdgcn_mfma_f32_16x16x32_bf16(A1, Bf1, pfr3, 0, 0, 0);

        if (bh < B) {
            float* Sb = out_cov + (size_t)bh * 1024 + (gp * 4) * 32 + ch;
#pragma unroll
            for (int j = 0; j < 4; ++j) {
                Sb[j * 32]       = s00[j];
                Sb[j * 32 + 16]  = s01[j];
                Sb[j * 32 + 512] = s10[j];
                Sb[j * 32 + 528] = s11[j];
            }
        }
    }
}

extern "C" void kernel_launch(void* const* d_in, const int* in_sizes, int n_in,
                              void* d_out, int out_size, void* d_ws, size_t ws_size,
                              hipStream_t stream)
{
    const float* obs   = (const float*)d_in[0];   // [B,16]
    const float* noise = (const float*)d_in[1];   // [B,16,16]
    const float* H     = (const float*)d_in[2];   // [16,32]
    const float* bias  = (const float*)d_in[3];   // [16]
    const float* mu0   = (const float*)d_in[4];   // [32]
    const float* P     = (const float*)d_in[5];   // [32,32]
    float* ws = (float*)d_ws;

    const int B = in_sizes[0] / 16;
    float* out_mean = (float*)d_out;
    float* out_cov  = out_mean + (size_t)B * 32;

    lgs_setup<<<1, 64, 0, stream>>>(H, bias, mu0, P, ws);
    lgs_main<<<(B + 31) / 32, 512, 0, stream>>>(obs, noise, ws, out_mean, out_cov, B);
}